// Round 1
// baseline (71.835 us; speedup 1.0000x reference)
//
#include <hip/hip_runtime.h>

// Problem constants (from reference setup_inputs)
constexpr int B_  = 8;
constexpr int T_  = 16;
constexpr int C_  = 256;
constexpr int HW_ = 784;   // 28*28
constexpr int CO_ = 64;    // C/4
constexpr int K_  = 7;     // KSZ
constexpr int U2_ = 32;    // 2*T

// ---------------------------------------------------------------------------
// Kernel 1: adaptive avg pool over (h,w): pooled[b,c,t] = mean(x[b,t,c,:,:])
// One wave per (b,t,c) slice of 784 contiguous floats. 4 waves per block.
// ---------------------------------------------------------------------------
__global__ __launch_bounds__(256) void pool_kernel(const float* __restrict__ x,
                                                   float* __restrict__ pooled) {
    int bid  = blockIdx.x;          // (b*T + t)*(C/4) + cg
    int cg   = bid & 63;
    int bt   = bid >> 6;            // b*T + t
    int t    = bt & 15;
    int b    = bt >> 4;
    int wave = threadIdx.x >> 6;
    int lane = threadIdx.x & 63;
    int c    = cg * 4 + wave;

    const float4* p4 = (const float4*)(x + ((size_t)bt * C_ + c) * HW_);
    float s = 0.f;
    for (int j = lane; j < 196; j += 64) {   // 196 float4 = 784 floats
        float4 v = p4[j];
        s += (v.x + v.y) + (v.z + v.w);
    }
#pragma unroll
    for (int m = 32; m >= 1; m >>= 1) s += __shfl_xor(s, m, 64);
    if (lane == 0) pooled[((size_t)b * C_ + c) * T_ + t] = s * (1.0f / 784.0f);
}

// ---------------------------------------------------------------------------
// Kernel 2: L-branch conv1d (C -> C/4, k=7, pad=3) + tanh
// ty[b,o,t] = tanh( sum_{i,k} pooled[b,i,t+k-3] * Wl1[o,i,k] )
// One block per (b,o); 256 threads = 16 t-groups x 16 i-splitters.
// ---------------------------------------------------------------------------
__global__ __launch_bounds__(256) void ty_kernel(const float* __restrict__ pooled,
                                                 const float* __restrict__ Wl1,
                                                 float* __restrict__ ty) {
    int b = blockIdx.x / CO_;
    int o = blockIdx.x % CO_;
    __shared__ float pld[T_ * 257];   // pld[t*257 + i], padded pitch

    int tid = threadIdx.x;
    for (int idx = tid; idx < C_ * T_; idx += 256) {
        int i  = idx >> 4;
        int tt = idx & 15;
        pld[tt * 257 + i] = pooled[((size_t)b * C_ + i) * T_ + tt];
    }
    __syncthreads();

    int t = tid >> 4;   // 0..15
    int q = tid & 15;   // i-split
    const float* wrow = Wl1 + (size_t)o * (C_ * K_);
    float acc = 0.f;
    for (int j = 0; j < 16; ++j) {
        int i = j * 16 + q;
        const float* wp = wrow + i * K_;
#pragma unroll
        for (int k = 0; k < K_; ++k) {
            int tt = t + k - 3;
            if (tt >= 0 && tt < T_) acc += wp[k] * pld[tt * 257 + i];
        }
    }
    acc += __shfl_xor(acc, 1, 64);
    acc += __shfl_xor(acc, 2, 64);
    acc += __shfl_xor(acc, 4, 64);
    acc += __shfl_xor(acc, 8, 64);
    if (q == 0) ty[((size_t)b * CO_ + o) * T_ + t] = tanhf(acc);
}

// ---------------------------------------------------------------------------
// Kernel 3: per-(b,c) block.
// Prologue: local[t] = sigmoid(Wl2[c,:] . ty[b,:,t]);
//           kw[k] = softmax_k( W2 . tanh(W1 . pooled[b,c,:]) );
//           A[t][t'] = kw[t'-t+3] * local[t']  (0 outside the 7-tap window)
// Main:     out[b,t,c,hw] = sum_{t'} A[t][t'] * x[b,t',c,hw]
// ---------------------------------------------------------------------------
__global__ __launch_bounds__(256) void tam_main_kernel(const float* __restrict__ x,
                                                       const float* __restrict__ pooled,
                                                       const float* __restrict__ ty,
                                                       const float* __restrict__ W1,
                                                       const float* __restrict__ W2,
                                                       const float* __restrict__ Wl2,
                                                       float* __restrict__ out) {
    int bc = blockIdx.x;        // b*C + c
    int b  = bc >> 8;
    int c  = bc & 255;
    int tid = threadIdx.x;

    __shared__ float loc_s[T_];
    __shared__ float g_s[U2_];
    __shared__ float s_s[K_];
    __shared__ float kw_s[K_];
    __shared__ float A_s[T_ * T_];

    // local[t]: 16 t-groups x 16 o-splitters (4 o each)
    {
        int t = tid >> 4, q = tid & 15;
        float acc = 0.f;
#pragma unroll
        for (int jj = 0; jj < 4; ++jj) {
            int o = q + jj * 16;
            acc += Wl2[(size_t)c * CO_ + o] * ty[((size_t)b * CO_ + o) * T_ + t];
        }
        acc += __shfl_xor(acc, 1, 64);
        acc += __shfl_xor(acc, 2, 64);
        acc += __shfl_xor(acc, 4, 64);
        acc += __shfl_xor(acc, 8, 64);
        if (q == 0) loc_s[t] = 1.0f / (1.0f + __expf(-acc));
    }
    // g[u] = tanh(pooled[b,c,:] . W1[u,:])
    if (tid < U2_) {
        float acc = 0.f;
#pragma unroll
        for (int t2 = 0; t2 < T_; ++t2)
            acc += pooled[((size_t)b * C_ + c) * T_ + t2] * W1[tid * T_ + t2];
        g_s[tid] = tanhf(acc);
    }
    __syncthreads();
    // s[k] = g . W2[k,:]
    if (tid < K_) {
        float acc = 0.f;
#pragma unroll
        for (int u = 0; u < U2_; ++u) acc += g_s[u] * W2[tid * U2_ + u];
        s_s[tid] = acc;
    }
    __syncthreads();
    // softmax over k (serial in thread 0; 7 elements)
    if (tid == 0) {
        float m = s_s[0];
#pragma unroll
        for (int k = 1; k < K_; ++k) m = fmaxf(m, s_s[k]);
        float e[K_], sum = 0.f;
#pragma unroll
        for (int k = 0; k < K_; ++k) { e[k] = __expf(s_s[k] - m); sum += e[k]; }
        float inv = 1.0f / sum;
#pragma unroll
        for (int k = 0; k < K_; ++k) kw_s[k] = e[k] * inv;
    }
    __syncthreads();
    // A[t][t'] = kw[t'-t+3] * loc[t']
    {
        int t = tid >> 4, tp = tid & 15;
        int d = tp - t + 3;
        A_s[tid] = (d >= 0 && d < K_) ? kw_s[d] * loc_s[tp] : 0.f;
    }
    __syncthreads();

    // Main streaming loop: 196 threads, one float4 (4 hw) each across all 16 t.
    if (tid < 196) {
        size_t base = ((size_t)(b * T_) * C_ + c) * HW_;  // (b, t'=0, c, hw=0)
        const size_t tstride = (size_t)C_ * HW_;          // stride per t'

        float4 xv[T_];
#pragma unroll
        for (int tp = 0; tp < T_; ++tp) {
            const float4* xp = (const float4*)(x + base + (size_t)tp * tstride);
            xv[tp] = xp[tid];
        }
#pragma unroll
        for (int t = 0; t < T_; ++t) {
            float4 acc = make_float4(0.f, 0.f, 0.f, 0.f);
#pragma unroll
            for (int d = -3; d <= 3; ++d) {
                int tp = t + d;
                if (tp >= 0 && tp < T_) {
                    float a = A_s[t * T_ + tp];
                    acc.x += a * xv[tp].x;
                    acc.y += a * xv[tp].y;
                    acc.z += a * xv[tp].z;
                    acc.w += a * xv[tp].w;
                }
            }
            float4* op = (float4*)(out + base + (size_t)t * tstride);
            op[tid] = acc;
        }
    }
}

extern "C" void kernel_launch(void* const* d_in, const int* in_sizes, int n_in,
                              void* d_out, int out_size, void* d_ws, size_t ws_size,
                              hipStream_t stream) {
    const float* x   = (const float*)d_in[0];
    const float* W1  = (const float*)d_in[1];
    const float* W2  = (const float*)d_in[2];
    const float* Wl1 = (const float*)d_in[3];
    const float* Wl2 = (const float*)d_in[4];
    float* out = (float*)d_out;

    float* pooled = (float*)d_ws;              // B*C*T = 32768 floats
    float* ty     = pooled + B_ * C_ * T_;     // B*CO*T = 8192 floats

    pool_kernel<<<B_ * T_ * (C_ / 4), 256, 0, stream>>>(x, pooled);
    ty_kernel<<<B_ * CO_, 256, 0, stream>>>(pooled, Wl1, ty);
    tam_main_kernel<<<B_ * C_, 256, 0, stream>>>(x, pooled, ty, W1, W2, Wl2, out);
}